// Round 1
// 438.648 us; speedup vs baseline: 1.0599x; 1.0599x over previous
//
#include <hip/hip_runtime.h>
#include <cstdint>

typedef _Float16 f16x8 __attribute__((ext_vector_type(8)));
typedef float f32x4 __attribute__((ext_vector_type(4)));

typedef __attribute__((address_space(1))) void gvoid;
typedef __attribute__((address_space(3))) void lvoid;

__device__ __forceinline__ void gload16(const void* g, void* l) {
    __builtin_amdgcn_global_load_lds((gvoid*)g, (lvoid*)l, 16, 0, 0);
}

__device__ __forceinline__ void bar() {
    asm volatile("" ::: "memory");
    __builtin_amdgcn_s_barrier();
    asm volatile("" ::: "memory");
}
#define WAITV(N) asm volatile("s_waitcnt vmcnt(" #N ")" ::: "memory")

// ---------------------------------------------------------------------------
// Downsample f,b (::2,::2) into compact fp32 planes ds[bb][c][a][v].
__global__ __launch_bounds__(256) void downsample_kernel(const float* __restrict__ f,
                                                         const float* __restrict__ b,
                                                         float* __restrict__ fds,
                                                         float* __restrict__ bds) {
    int idx = blockIdx.x * 256 + threadIdx.x;
    const float* src = blockIdx.y ? b : f;
    float* dst = blockIdx.y ? bds : fds;
    int bb = idx >> 19;
    int r = idx & 524287;
    int c = r >> 12, a = (r >> 6) & 63, v = r & 63;
    dst[idx] = src[(size_t)bb * 2097152 + (size_t)c * 16384 + (2 * a) * 128 + 2 * v];
}

// ---------------------------------------------------------------------------
__global__ __launch_bounds__(256) void build_mm_kernel(const float* __restrict__ mask,
                                                       float* __restrict__ mm) {
    int l = blockIdx.x * 256 + threadIdx.x;
    if (l >= 4096) return;
    int i = l >> 6, j = l & 63;
    float s = 0.f;
    #pragma unroll
    for (int dy = 0; dy < 3; ++dy)
        #pragma unroll
        for (int dx = 0; dx < 3; ++dx) {
            int a = i + dy - 1, b = j + dx - 1;
            if ((unsigned)a < 64u && (unsigned)b < 64u)
                s += mask[(2 * a) * 128 + 2 * b];
        }
    mm[l] = (s == 0.0f) ? 1.0f : 0.0f;
}

// ---------------------------------------------------------------------------
// Both batches: grid 8192. K-order k = c*9 + s. Reads L2-hot f_ds.
__global__ __launch_bounds__(256) void build_fpatch_kernel(const float* __restrict__ fds,
                                                           _Float16* __restrict__ Fp) {
    int bb = blockIdx.x >> 12;
    int p = blockIdx.x & 4095;
    const float* fb = fds + (size_t)bb * 524288;
    _Float16* Fpb = Fp + (size_t)bb * 4718592;
    int u = p >> 6, v = p & 63;
    for (int k = threadIdx.x; k < 1152; k += 256) {
        int c = k / 9;
        int s = k - 9 * c;
        int dy = s / 3, dx = s - 3 * dy;
        int a = u + dy - 1, bcol = v + dx - 1;
        float val = 0.f;
        if ((unsigned)a < 64u && (unsigned)bcol < 64u)
            val = fb[c * 4096 + a * 64 + bcol];
        Fpb[(size_t)p * 1152 + k] = (_Float16)val;
    }
}

// ---------------------------------------------------------------------------
__global__ __launch_bounds__(256) void build_wn_kernel(const float* __restrict__ bds,
                                                       _Float16* __restrict__ Wn) {
    __shared__ float wsh[1152];
    __shared__ float red[4];
    int bb = blockIdx.x >> 12;
    int l = blockIdx.x & 4095;
    const float* bp = bds + (size_t)bb * 524288;
    _Float16* Wnb = Wn + (size_t)bb * 4718592;
    int i = l >> 6, j = l & 63;
    float sq = 0.f;
    for (int k = threadIdx.x; k < 1152; k += 256) {
        int c = k / 9;
        int s = k - 9 * c;
        int dy = s / 3, dx = s - 3 * dy;
        int a = i + dy - 1, bcol = j + dx - 1;
        float val = 0.f;
        if ((unsigned)a < 64u && (unsigned)bcol < 64u)
            val = bp[c * 4096 + a * 64 + bcol];
        wsh[k] = val;
        sq += val * val;
    }
    #pragma unroll
    for (int off = 32; off > 0; off >>= 1) sq += __shfl_xor(sq, off);
    if ((threadIdx.x & 63) == 0) red[threadIdx.x >> 6] = sq;
    __syncthreads();
    float total = red[0] + red[1] + red[2] + red[3] + 0.1152f;
    float rinv = 1.0f / sqrtf(total);
    for (int k = threadIdx.x; k < 1152; k += 256)
        Wnb[(size_t)l * 1152 + k] = (_Float16)(wsh[k] * rinv);
}

// ---------------------------------------------------------------------------
__global__ __launch_bounds__(256) void build_vt_kernel(const float* __restrict__ b,
                                                       _Float16* __restrict__ Vt) {
    int bb = blockIdx.x >> 11;
    int n = blockIdx.x & 2047;
    const float* bp = b + (size_t)bb * 2097152;
    _Float16* Vtb = Vt + (size_t)bb * 8388608;
    int c = n >> 4, r = n & 15, rh = r >> 2, rw = r & 3;
    const float* bc = bp + (size_t)c * 16384;
    for (int l = threadIdx.x; l < 4096; l += 256) {
        int lh = l >> 6, lw = l & 63;
        int row = 2 * lh + rh - 1, col = 2 * lw + rw - 1;
        float val = 0.f;
        if ((unsigned)row < 128u && (unsigned)col < 128u)
            val = bc[row * 128 + col];
        Vtb[(size_t)n * 4096 + l] = (_Float16)val;
    }
}

// ---------------------------------------------------------------------------
// GEMM1 batched over z: S0[z][4096][4096] f16 = Fp[z] * Wn[z]^T, fp32 accum.
// (m97 structure, BK=32 — unchanged this round for attribution.)
__global__ __launch_bounds__(256) void gemm1_kernel(const _Float16* __restrict__ Fp,
                                                    const _Float16* __restrict__ Wn,
                                                    _Float16* __restrict__ S0) {
    __shared__ __align__(16) _Float16 As[128 * 32];
    __shared__ __align__(16) _Float16 Bs[128 * 32];
    const int z = blockIdx.z;
    const _Float16* A = Fp + (size_t)z * 4718592;
    const _Float16* Bt = Wn + (size_t)z * 4718592;
    _Float16* C = S0 + (size_t)z * 16777216;
    const int tid = threadIdx.x;
    const int lane = tid & 63;
    const int wave = tid >> 6;
    const int quad = lane >> 4;
    const int l16 = lane & 15;
    const int bm = blockIdx.y * 128;
    const int bn = blockIdx.x * 128;
    const int waveM = (wave >> 1) * 64;
    const int waveN = (wave & 1) * 64;
    const int K = 1152;

    f32x4 acc[4][4] = {};

    const int rowS = tid >> 2;
    const int colS = (tid & 3) * 8;

    for (int k0 = 0; k0 < K; k0 += 32) {
        #pragma unroll
        for (int i = 0; i < 2; ++i) {
            const _Float16* g = A + (size_t)(bm + i * 64 + rowS) * K + k0 + colS;
            gload16(g, &As[i * 2048 + tid * 8]);
        }
        #pragma unroll
        for (int i = 0; i < 2; ++i) {
            const _Float16* g = Bt + (size_t)(bn + i * 64 + rowS) * K + k0 + colS;
            gload16(g, &Bs[i * 2048 + tid * 8]);
        }
        __syncthreads();
        f16x8 a_frag[4], b_frag[4];
        #pragma unroll
        for (int mi = 0; mi < 4; ++mi)
            a_frag[mi] = *(const f16x8*)&As[(waveM + mi * 16 + l16) * 32 + quad * 8];
        #pragma unroll
        for (int ni = 0; ni < 4; ++ni)
            b_frag[ni] = *(const f16x8*)&Bs[(waveN + ni * 16 + l16) * 32 + quad * 8];
        #pragma unroll
        for (int mi = 0; mi < 4; ++mi)
            #pragma unroll
            for (int ni = 0; ni < 4; ++ni)
                acc[mi][ni] = __builtin_amdgcn_mfma_f32_16x16x32_f16(
                    a_frag[mi], b_frag[ni], acc[mi][ni], 0, 0, 0);
        __syncthreads();
    }

    #pragma unroll
    for (int mi = 0; mi < 4; ++mi)
        #pragma unroll
        for (int ni = 0; ni < 4; ++ni)
            #pragma unroll
            for (int r = 0; r < 4; ++r) {
                int row = bm + waveM + mi * 16 + quad * 4 + r;
                int col = bn + waveN + ni * 16 + l16;
                C[(size_t)row * 4096 + col] = (_Float16)acc[mi][ni][r];
            }
}

// ---------------------------------------------------------------------------
// GEMM2: 256x256 tile, BK=64, 8 waves, 8-phase schedule with counted vmcnt
// (T3+T4) + setprio (T5), swizzled conflict-free LDS (T2).
//
// LDS regions: per operand, 2 buffers x 2 K-half regions [256 rows][32 K]
// (16 KB each), 128 KiB total. Reads staggered: phases 1-2 read buf0.Kh0,
// 3-4 buf0.Kh1, 5-6 buf1.Kh0, 7-8 buf1.Kh1. Each region's re-stage is issued
// exactly one phase after its last read (WAR-safe: all waves' ds_reads retire
// before their end-of-phase barrier). Completion is guaranteed by vmcnt(4)
// at phases 4 and 8 only (2 half-tile units = 4 loads/wave stay in flight;
// never a vmcnt(0) drain in the main loop).
//   issue(i,p1/p2): buf1.Kh1 <- tile 2i+1   (read at i,p7/p8)
//   issue(i,p3/p4): buf0.Kh0 <- tile 2i+2   (read at i+1,p1/p2)
//   issue(i,p5/p6): buf0.Kh1 <- tile 2i+2   (read at i+1,p3/p4)
//   issue(i,p7/p8): buf1.Kh0 <- tile 2i+3   (read at i+1,p5/p6)
// Swizzle (both-sides rule, m173): slot granule s=(sr,sg) holds logical
// (r = sr ^ ((sr>>2)&1), q = sg ^ (r&3)); applied on the per-lane GLOBAL
// source address (LDS dest stays linear = wave base + lane*16), and inverted
// on the ds_read address. 8-lane cycle groups hit 8 distinct bank-groups.
// Raw s_barrier + asm waits (NOT __syncthreads -> would re-drain vmcnt(0)).
// Accumulation order per acc element identical to previous kernel (kh0 then
// kh1, ascending tiles) -> numerics unchanged.
__global__ __launch_bounds__(512, 2) void gemm2_kernel(const _Float16* __restrict__ Vt,
                                                       const _Float16* __restrict__ att0,
                                                       const _Float16* __restrict__ att1,
                                                       _Float16* __restrict__ OTh) {
    __shared__ __align__(16) _Float16 As[2][2][8192];   // [buf][kh][256*32]
    __shared__ __align__(16) _Float16 Bs[2][2][8192];
    const int z = blockIdx.z;
    const _Float16* A = Vt + (size_t)z * 8388608;
    const _Float16* Bt = z ? att1 : att0;
    _Float16* C = OTh + (size_t)z * 8388608;
    const int tid = threadIdx.x;
    const int lane = tid & 63;
    const int wave = tid >> 6;
    const int quad = lane >> 4;
    const int l16 = lane & 15;
    const int wm = wave >> 2;   // 0..1 -> 128-row half of M-tile
    const int wn = wave & 3;    // 0..3 -> 64-col slice of N-tile
    const int bm = blockIdx.y * 256;
    const int bn = blockIdx.x * 256;

    f32x4 acc[8][4] = {};
    f16x8 afr[4], bfr[4];

    // --- staging source offsets (pre-swizzled global addresses, m173) ---
    // slot s = rd*512 + tid; sr = s>>2; sg = s&3;
    // logical r = sr ^ ((sr>>2)&1); q = sg ^ (r&3)
    const int s0 = tid, s1 = 512 + tid;
    const int sr0 = s0 >> 2, sr1 = s1 >> 2;
    const int r0 = sr0 ^ ((sr0 >> 2) & 1);
    const int r1 = sr1 ^ ((sr1 >> 2) & 1);
    const int q0 = (s0 & 3) ^ (r0 & 3);
    const int q1 = (s1 & 3) ^ (r1 & 3);
    const int offA0 = (bm + r0) * 4096 + q0 * 8;
    const int offA1 = (bm + r1) * 4096 + q1 * 8;
    const int offB0 = (bn + r0) * 4096 + q0 * 8;
    const int offB1 = (bn + r1) * 4096 + q1 * 8;

#define STAGE_A(buf, kt, kh) do {                                          \
        gload16(A + offA0 + (kt) * 64 + (kh) * 32, &As[buf][kh][tid * 8]); \
        gload16(A + offA1 + (kt) * 64 + (kh) * 32, &As[buf][kh][4096 + tid * 8]); \
    } while (0)
#define STAGE_B(buf, kt, kh) do {                                          \
        gload16(Bt + offB0 + (kt) * 64 + (kh) * 32, &Bs[buf][kh][tid * 8]); \
        gload16(Bt + offB1 + (kt) * 64 + (kh) * 32, &Bs[buf][kh][4096 + tid * 8]); \
    } while (0)

    // --- ds_read swizzle (inverse of the stage permutation) ---
    // fragment row r = base16 + l16 (base16 % 16 == 0) ->
    //   sr = base16 + (l16 ^ ((l16>>2)&1)); sg = quad ^ (l16&3)
    const int c2 = (l16 >> 2) & 1;
    const int rdoff = ((l16 ^ c2) * 32) + ((quad ^ (l16 & 3)) * 8);  // halfs

    auto LDA = [&](int buf, int kh, int mh) {
        #pragma unroll
        for (int mi = 0; mi < 4; ++mi)
            afr[mi] = *(const f16x8*)&As[buf][kh][(wm * 128 + (mh * 4 + mi) * 16) * 32 + rdoff];
    };
    auto LDB = [&](int buf, int kh) {
        #pragma unroll
        for (int ni = 0; ni < 4; ++ni)
            bfr[ni] = *(const f16x8*)&Bs[buf][kh][(wn * 64 + ni * 16) * 32 + rdoff];
    };
    auto MM = [&](int mh) {
        __builtin_amdgcn_s_setprio(1);
        #pragma unroll
        for (int mi = 0; mi < 4; ++mi)
            #pragma unroll
            for (int ni = 0; ni < 4; ++ni)
                acc[mh * 4 + mi][ni] = __builtin_amdgcn_mfma_f32_16x16x32_f16(
                    afr[mi], bfr[ni], acc[mh * 4 + mi][ni], 0, 0, 0);
        __builtin_amdgcn_s_setprio(0);
    };

    // --- prologue: 6 half-tile units; keep last 2 in flight ---
    STAGE_A(0, 0, 0); STAGE_B(0, 0, 0);
    STAGE_A(0, 0, 1); STAGE_B(0, 0, 1);
    STAGE_A(1, 1, 0); STAGE_B(1, 1, 0);
    WAITV(4);
    bar();

    // --- main loop: 31 iters x 2 K-tiles (tiles 0..61), prefetch thru 63 ---
    #pragma unroll 1
    for (int i = 0; i < 31; ++i) {
        const int t0 = 2 * i;
        // p1
        LDA(0, 0, 0); LDB(0, 0); STAGE_A(1, t0 + 1, 1);
        bar(); MM(0); bar();
        // p2
        LDA(0, 0, 1); STAGE_B(1, t0 + 1, 1);
        bar(); MM(1); bar();
        // p3
        LDA(0, 1, 0); LDB(0, 1); STAGE_A(0, t0 + 2, 0);
        bar(); MM(0); bar();
        // p4
        LDA(0, 1, 1); STAGE_B(0, t0 + 2, 0);
        bar(); MM(1); WAITV(4); bar();
        // p5
        LDA(1, 0, 0); LDB(1, 0); STAGE_A(0, t0 + 2, 1);
        bar(); MM(0); bar();
        // p6
        LDA(1, 0, 1); STAGE_B(0, t0 + 2, 1);
        bar(); MM(1); bar();
        // p7
        LDA(1, 1, 0); LDB(1, 1); STAGE_A(1, t0 + 3, 0);
        bar(); MM(0); bar();
        // p8
        LDA(1, 1, 1); STAGE_B(1, t0 + 3, 0);
        bar(); MM(1); WAITV(4); bar();
    }

    // --- epilogue: tiles 62 (buf0), 63 (buf1); only buf1.Kh1 still to stage ---
    // p1
    LDA(0, 0, 0); LDB(0, 0); STAGE_A(1, 63, 1);
    bar(); MM(0); bar();
    // p2
    LDA(0, 0, 1); STAGE_B(1, 63, 1);
    bar(); MM(1); bar();
    // p3
    LDA(0, 1, 0); LDB(0, 1);
    bar(); MM(0); bar();
    // p4 — final drain (end of pipeline, one-time vmcnt(0) is fine here)
    LDA(0, 1, 1);
    bar(); MM(1); WAITV(0); bar();
    // p5..p8 on buf1 (tile 63)
    LDA(1, 0, 0); LDB(1, 0); bar(); MM(0); bar();
    LDA(1, 0, 1);            bar(); MM(1); bar();
    LDA(1, 1, 0); LDB(1, 1); bar(); MM(0); bar();
    LDA(1, 1, 1);            bar(); MM(1); bar();

#undef STAGE_A
#undef STAGE_B

    #pragma unroll
    for (int mi = 0; mi < 8; ++mi)
        #pragma unroll
        for (int ni = 0; ni < 4; ++ni)
            #pragma unroll
            for (int r = 0; r < 4; ++r) {
                int row = bm + wm * 128 + mi * 16 + quad * 4 + r;
                int col = bn + wn * 64 + ni * 16 + l16;
                C[(size_t)row * 4096 + col] = (_Float16)acc[mi][ni][r];
            }
}

// ---------------------------------------------------------------------------
// Fused double 3-tap "fuse" + mask + softmax (R8 body, XCD swizzle, both
// batches in one dispatch).
__global__ __launch_bounds__(256) void fuse_softmax_kernel(const _Float16* __restrict__ S0,
                                                           const float* __restrict__ mm,
                                                           _Float16* __restrict__ att0,
                                                           _Float16* __restrict__ att1) {
    __shared__ float red[4];
    const int tid = threadIdx.x;
    const int lane = tid & 63;
    const int wave = tid >> 6;
    int g = blockIdx.x;
    int p_global = ((g & 7) << 10) | (g >> 3);
    const int bb = p_global >> 12;
    const int p = p_global & 4095;
    const _Float16* S = S0 + (size_t)bb * 16777216;
    _Float16* att = bb ? att1 : att0;
    const int pbase = ((p & 63) << 6) | (p >> 6);  // T(p)

    float acc[16];
    #pragma unroll
    for (int k = 0; k < 16; ++k) acc[k] = 0.f;

    #pragma unroll
    for (int t2 = -1; t2 <= 1; ++t2) {
        int b2 = pbase + t2;
        if ((unsigned)b2 >= 4096u) continue;
        int pp = ((b2 & 63) << 6) | (b2 >> 6);
        #pragma unroll
        for (int t1 = -1; t1 <= 1; ++t1) {
            int rr = pp + t1;
            if ((unsigned)rr >= 4096u) continue;
            const _Float16* row = S + (size_t)rr * 4096;
            #pragma unroll
            for (int k = 0; k < 16; ++k) {
                int l = k * 256 + tid;
                int i = (k * 256 + wave * 64) >> 6;
                int it2 = i + t2;
                if (it2 >= 0 && it2 < 64) {
                    int c = l + t2 * 64 + t1;
                    if ((unsigned)c < 4096u)
                        acc[k] += (float)row[c];
                } else if (it2 == 64) {
                    if (lane <= 62) {
                        int c = lane + 1 + t1;
                        if ((unsigned)c < 4096u) acc[k] += (float)row[c];
                    }
                } else {
                    if (lane >= 1) {
                        int c = 4031 + lane + t1;
                        if ((unsigned)c < 4096u) acc[k] += (float)row[c];
                    }
                }
            }
        }
    }

    float mv[16];
    float lmax = -1e30f;
    #pragma unroll
    for (int k = 0; k < 16; ++k) {
        int l = k * 256 + tid;
        mv[k] = mm[l];
        float lg = acc[k] * mv[k] * 10.0f;
        acc[k] = lg;
        lmax = fmaxf(lmax, lg);
    }
    #pragma unroll
    for (int off = 32; off > 0; off >>= 1) lmax = fmaxf(lmax, __shfl_xor(lmax, off));
    if (lane == 0) red[wave] = lmax;
    __syncthreads();
    lmax = fmaxf(fmaxf(red[0], red[1]), fmaxf(red[2], red[3]));
    __syncthreads();

    float lsum = 0.f;
    #pragma unroll
    for (int k = 0; k < 16; ++k) {
        float e = __expf(acc[k] - lmax);
        acc[k] = e;
        lsum += e;
    }
    #pragma unroll
    for (int off = 32; off > 0; off >>= 1) lsum += __shfl_xor(lsum, off);
    if (lane == 0) red[wave] = lsum;
    __syncthreads();
    float inv = 1.0f / (red[0] + red[1] + red[2] + red[3]);
    #pragma unroll
    for (int k = 0; k < 16; ++k) {
        int l = k * 256 + tid;
        att[(size_t)p * 4096 + l] = (_Float16)(acc[k] * inv * mv[k]);
    }
}

// ---------------------------------------------------------------------------
__global__ __launch_bounds__(256) void assemble_kernel(const _Float16* __restrict__ OTh,
                                                       float* __restrict__ out) {
    int idx = blockIdx.x * 256 + threadIdx.x;
    int bb = idx >> 21;
    int w = idx & 2097151;
    const _Float16* OTb = OTh + (size_t)bb * 8388608;
    int x = w & 127, y = (w >> 7) & 127, c = w >> 14;
    int r0 = (y + 1) & 1, s0 = (x + 1) & 1;
    float acc = 0.f;
    #pragma unroll
    for (int a = 0; a < 2; ++a) {
        int rh = r0 + 2 * a;
        int ph = (y + 1 - rh) >> 1;
        if ((unsigned)ph < 64u) {
            #pragma unroll
            for (int bq = 0; bq < 2; ++bq) {
                int rw = s0 + 2 * bq;
                int pw = (x + 1 - rw) >> 1;
                if ((unsigned)pw < 64u)
                    acc += (float)OTb[(size_t)(c * 16 + rh * 4 + rw) * 4096 + ph * 64 + pw];
            }
        }
    }
    out[idx] = 0.25f * acc;
}

// ---------------------------------------------------------------------------
extern "C" void kernel_launch(void* const* d_in, const int* in_sizes, int n_in,
                              void* d_out, int out_size, void* d_ws, size_t ws_size,
                              hipStream_t stream) {
    const float* f = (const float*)d_in[0];
    const float* b = (const float*)d_in[1];
    const float* mask = (const float*)d_in[2];
    float* out = (float*)d_out;
    char* ws = (char*)d_ws;

    // workspace — total 138,428,416 bytes (proven size)
    //   mm   : ws + 0              (16 KB)
    //   A    : ws + 16384          (37,748,736)  Fp+Wn  -> att0 (33.55M) after gemm1
    //   B    : ws + 37,765,120     (67,108,864)  S0(2x) -> Vt + OTh after fuse
    //   C    : ws + 104,873,984    (33,554,432)  fds/bds (8MB) -> att1
    float* mm = (float*)ws;
    _Float16* Fp = (_Float16*)(ws + 16384);
    _Float16* Wn = (_Float16*)(ws + 16384 + 18874368);
    _Float16* att0 = (_Float16*)(ws + 16384);                 // overlays Fp/Wn (dead)
    _Float16* S0 = (_Float16*)(ws + 37765120);
    _Float16* Vt = (_Float16*)(ws + 37765120);                // overlays S0 b0 (dead)
    _Float16* OTh = (_Float16*)(ws + 37765120 + 33554432);    // overlays S0 b1 (dead)
    float* fds = (float*)(ws + 104873984);
    float* bds = (float*)(ws + 104873984 + 4194304);
    _Float16* att1 = (_Float16*)(ws + 104873984);             // overlays fds/bds (dead)

    downsample_kernel<<<dim3(4096, 2), 256, 0, stream>>>(f, b, fds, bds);
    build_mm_kernel<<<16, 256, 0, stream>>>(mask, mm);
    build_fpatch_kernel<<<8192, 256, 0, stream>>>(fds, Fp);
    build_wn_kernel<<<8192, 256, 0, stream>>>(bds, Wn);

    gemm1_kernel<<<dim3(32, 32, 2), 256, 0, stream>>>(Fp, Wn, S0);
    fuse_softmax_kernel<<<8192, 256, 0, stream>>>(S0, mm, att0, att1);

    build_vt_kernel<<<4096, 256, 0, stream>>>(b, Vt);
    gemm2_kernel<<<dim3(16, 8, 2), 512, 0, stream>>>(Vt, att0, att1, OTh);
    assemble_kernel<<<16384, 256, 0, stream>>>(OTh, out);
}

// Round 2
// 434.160 us; speedup vs baseline: 1.0709x; 1.0103x over previous
//
#include <hip/hip_runtime.h>
#include <cstdint>

typedef _Float16 f16x8 __attribute__((ext_vector_type(8)));
typedef float f32x4 __attribute__((ext_vector_type(4)));

typedef __attribute__((address_space(1))) void gvoid;
typedef __attribute__((address_space(3))) void lvoid;

__device__ __forceinline__ void gload16(const void* g, void* l) {
    __builtin_amdgcn_global_load_lds((gvoid*)g, (lvoid*)l, 16, 0, 0);
}

__device__ __forceinline__ void bar() {
    asm volatile("" ::: "memory");
    __builtin_amdgcn_s_barrier();
    asm volatile("" ::: "memory");
}
#define WAITV(N) asm volatile("s_waitcnt vmcnt(" #N ")" ::: "memory")

// ---------------------------------------------------------------------------
// Downsample f,b (::2,::2) into compact fp32 planes ds[bb][c][a][v].
__global__ __launch_bounds__(256) void downsample_kernel(const float* __restrict__ f,
                                                         const float* __restrict__ b,
                                                         float* __restrict__ fds,
                                                         float* __restrict__ bds) {
    int idx = blockIdx.x * 256 + threadIdx.x;
    const float* src = blockIdx.y ? b : f;
    float* dst = blockIdx.y ? bds : fds;
    int bb = idx >> 19;
    int r = idx & 524287;
    int c = r >> 12, a = (r >> 6) & 63, v = r & 63;
    dst[idx] = src[(size_t)bb * 2097152 + (size_t)c * 16384 + (2 * a) * 128 + 2 * v];
}

// ---------------------------------------------------------------------------
__global__ __launch_bounds__(256) void build_mm_kernel(const float* __restrict__ mask,
                                                       float* __restrict__ mm) {
    int l = blockIdx.x * 256 + threadIdx.x;
    if (l >= 4096) return;
    int i = l >> 6, j = l & 63;
    float s = 0.f;
    #pragma unroll
    for (int dy = 0; dy < 3; ++dy)
        #pragma unroll
        for (int dx = 0; dx < 3; ++dx) {
            int a = i + dy - 1, b = j + dx - 1;
            if ((unsigned)a < 64u && (unsigned)b < 64u)
                s += mask[(2 * a) * 128 + 2 * b];
        }
    mm[l] = (s == 0.0f) ? 1.0f : 0.0f;
}

// ---------------------------------------------------------------------------
// Both batches: grid 8192. K-order k = c*9 + s. Reads L2-hot f_ds.
__global__ __launch_bounds__(256) void build_fpatch_kernel(const float* __restrict__ fds,
                                                           _Float16* __restrict__ Fp) {
    int bb = blockIdx.x >> 12;
    int p = blockIdx.x & 4095;
    const float* fb = fds + (size_t)bb * 524288;
    _Float16* Fpb = Fp + (size_t)bb * 4718592;
    int u = p >> 6, v = p & 63;
    for (int k = threadIdx.x; k < 1152; k += 256) {
        int c = k / 9;
        int s = k - 9 * c;
        int dy = s / 3, dx = s - 3 * dy;
        int a = u + dy - 1, bcol = v + dx - 1;
        float val = 0.f;
        if ((unsigned)a < 64u && (unsigned)bcol < 64u)
            val = fb[c * 4096 + a * 64 + bcol];
        Fpb[(size_t)p * 1152 + k] = (_Float16)val;
    }
}

// ---------------------------------------------------------------------------
__global__ __launch_bounds__(256) void build_wn_kernel(const float* __restrict__ bds,
                                                       _Float16* __restrict__ Wn) {
    __shared__ float wsh[1152];
    __shared__ float red[4];
    int bb = blockIdx.x >> 12;
    int l = blockIdx.x & 4095;
    const float* bp = bds + (size_t)bb * 524288;
    _Float16* Wnb = Wn + (size_t)bb * 4718592;
    int i = l >> 6, j = l & 63;
    float sq = 0.f;
    for (int k = threadIdx.x; k < 1152; k += 256) {
        int c = k / 9;
        int s = k - 9 * c;
        int dy = s / 3, dx = s - 3 * dy;
        int a = i + dy - 1, bcol = j + dx - 1;
        float val = 0.f;
        if ((unsigned)a < 64u && (unsigned)bcol < 64u)
            val = bp[c * 4096 + a * 64 + bcol];
        wsh[k] = val;
        sq += val * val;
    }
    #pragma unroll
    for (int off = 32; off > 0; off >>= 1) sq += __shfl_xor(sq, off);
    if ((threadIdx.x & 63) == 0) red[threadIdx.x >> 6] = sq;
    __syncthreads();
    float total = red[0] + red[1] + red[2] + red[3] + 0.1152f;
    float rinv = 1.0f / sqrtf(total);
    for (int k = threadIdx.x; k < 1152; k += 256)
        Wnb[(size_t)l * 1152 + k] = (_Float16)(wsh[k] * rinv);
}

// ---------------------------------------------------------------------------
__global__ __launch_bounds__(256) void build_vt_kernel(const float* __restrict__ b,
                                                       _Float16* __restrict__ Vt) {
    int bb = blockIdx.x >> 11;
    int n = blockIdx.x & 2047;
    const float* bp = b + (size_t)bb * 2097152;
    _Float16* Vtb = Vt + (size_t)bb * 8388608;
    int c = n >> 4, r = n & 15, rh = r >> 2, rw = r & 3;
    const float* bc = bp + (size_t)c * 16384;
    for (int l = threadIdx.x; l < 4096; l += 256) {
        int lh = l >> 6, lw = l & 63;
        int row = 2 * lh + rh - 1, col = 2 * lw + rw - 1;
        float val = 0.f;
        if ((unsigned)row < 128u && (unsigned)col < 128u)
            val = bc[row * 128 + col];
        Vtb[(size_t)n * 4096 + l] = (_Float16)val;
    }
}

// ---------------------------------------------------------------------------
// GEMM1: S0[z][4096][4096] f16 = Fp[z] * Wn[z]^T, fp32 accum. Ported to the
// 8-phase 256x256 template proven on gemm2 (R1): BK=64, 8 waves, counted
// vmcnt (never 0 in main loop), setprio around MFMA bursts, swizzled LDS.
// K=1152 -> 18 K-tiles of 64 -> 8 main iters (tiles 0..15) + epilogue (16,17).
// Accumulation chunk order = ascending 32-K, identical to the old BK=32 loop.
__global__ __launch_bounds__(512, 2) void gemm1_kernel(const _Float16* __restrict__ Fp,
                                                       const _Float16* __restrict__ Wn,
                                                       _Float16* __restrict__ S0) {
    __shared__ __align__(16) _Float16 As[2][2][8192];   // [buf][kh][256*32]
    __shared__ __align__(16) _Float16 Bs[2][2][8192];
    const int z = blockIdx.z;
    const _Float16* A = Fp + (size_t)z * 4718592;
    const _Float16* Bt = Wn + (size_t)z * 4718592;
    _Float16* C = S0 + (size_t)z * 16777216;
    const int tid = threadIdx.x;
    const int lane = tid & 63;
    const int wave = tid >> 6;
    const int quad = lane >> 4;
    const int l16 = lane & 15;
    const int wm = wave >> 2;
    const int wn = wave & 3;
    const int bm = blockIdx.y * 256;
    const int bn = blockIdx.x * 256;

    f32x4 acc[8][4] = {};
    f16x8 afr[4], bfr[4];

    const int s0 = tid, s1 = 512 + tid;
    const int sr0 = s0 >> 2, sr1 = s1 >> 2;
    const int r0 = sr0 ^ ((sr0 >> 2) & 1);
    const int r1 = sr1 ^ ((sr1 >> 2) & 1);
    const int q0 = (s0 & 3) ^ (r0 & 3);
    const int q1 = (s1 & 3) ^ (r1 & 3);
    const int offA0 = (bm + r0) * 1152 + q0 * 8;
    const int offA1 = (bm + r1) * 1152 + q1 * 8;
    const int offB0 = (bn + r0) * 1152 + q0 * 8;
    const int offB1 = (bn + r1) * 1152 + q1 * 8;

#define STAGE_A(buf, kt, kh) do {                                          \
        gload16(A + offA0 + (kt) * 64 + (kh) * 32, &As[buf][kh][tid * 8]); \
        gload16(A + offA1 + (kt) * 64 + (kh) * 32, &As[buf][kh][4096 + tid * 8]); \
    } while (0)
#define STAGE_B(buf, kt, kh) do {                                          \
        gload16(Bt + offB0 + (kt) * 64 + (kh) * 32, &Bs[buf][kh][tid * 8]); \
        gload16(Bt + offB1 + (kt) * 64 + (kh) * 32, &Bs[buf][kh][4096 + tid * 8]); \
    } while (0)

    const int c2 = (l16 >> 2) & 1;
    const int rdoff = ((l16 ^ c2) * 32) + ((quad ^ (l16 & 3)) * 8);

    auto LDA = [&](int buf, int kh, int mh) {
        #pragma unroll
        for (int mi = 0; mi < 4; ++mi)
            afr[mi] = *(const f16x8*)&As[buf][kh][(wm * 128 + (mh * 4 + mi) * 16) * 32 + rdoff];
    };
    auto LDB = [&](int buf, int kh) {
        #pragma unroll
        for (int ni = 0; ni < 4; ++ni)
            bfr[ni] = *(const f16x8*)&Bs[buf][kh][(wn * 64 + ni * 16) * 32 + rdoff];
    };
    auto MM = [&](int mh) {
        __builtin_amdgcn_s_setprio(1);
        #pragma unroll
        for (int mi = 0; mi < 4; ++mi)
            #pragma unroll
            for (int ni = 0; ni < 4; ++ni)
                acc[mh * 4 + mi][ni] = __builtin_amdgcn_mfma_f32_16x16x32_f16(
                    afr[mi], bfr[ni], acc[mh * 4 + mi][ni], 0, 0, 0);
        __builtin_amdgcn_s_setprio(0);
    };

    STAGE_A(0, 0, 0); STAGE_B(0, 0, 0);
    STAGE_A(0, 0, 1); STAGE_B(0, 0, 1);
    STAGE_A(1, 1, 0); STAGE_B(1, 1, 0);
    WAITV(4);
    bar();

    #pragma unroll 1
    for (int i = 0; i < 8; ++i) {
        const int t0 = 2 * i;
        LDA(0, 0, 0); LDB(0, 0); STAGE_A(1, t0 + 1, 1);
        bar(); MM(0); bar();
        LDA(0, 0, 1); STAGE_B(1, t0 + 1, 1);
        bar(); MM(1); bar();
        LDA(0, 1, 0); LDB(0, 1); STAGE_A(0, t0 + 2, 0);
        bar(); MM(0); bar();
        LDA(0, 1, 1); STAGE_B(0, t0 + 2, 0);
        bar(); MM(1); WAITV(4); bar();
        LDA(1, 0, 0); LDB(1, 0); STAGE_A(0, t0 + 2, 1);
        bar(); MM(0); bar();
        LDA(1, 0, 1); STAGE_B(0, t0 + 2, 1);
        bar(); MM(1); bar();
        LDA(1, 1, 0); LDB(1, 1); STAGE_A(1, t0 + 3, 0);
        bar(); MM(0); bar();
        LDA(1, 1, 1); STAGE_B(1, t0 + 3, 0);
        bar(); MM(1); WAITV(4); bar();
    }

    // epilogue: tiles 16 (buf0), 17 (buf1); only buf1.Kh1 still to stage
    LDA(0, 0, 0); LDB(0, 0); STAGE_A(1, 17, 1);
    bar(); MM(0); bar();
    LDA(0, 0, 1); STAGE_B(1, 17, 1);
    bar(); MM(1); bar();
    LDA(0, 1, 0); LDB(0, 1);
    bar(); MM(0); bar();
    LDA(0, 1, 1);
    bar(); MM(1); WAITV(0); bar();
    LDA(1, 0, 0); LDB(1, 0); bar(); MM(0); bar();
    LDA(1, 0, 1);            bar(); MM(1); bar();
    LDA(1, 1, 0); LDB(1, 1); bar(); MM(0); bar();
    LDA(1, 1, 1);            bar(); MM(1); bar();

#undef STAGE_A
#undef STAGE_B

    #pragma unroll
    for (int mi = 0; mi < 8; ++mi)
        #pragma unroll
        for (int ni = 0; ni < 4; ++ni)
            #pragma unroll
            for (int r = 0; r < 4; ++r) {
                int row = bm + wm * 128 + mi * 16 + quad * 4 + r;
                int col = bn + wn * 64 + ni * 16 + l16;
                C[(size_t)row * 4096 + col] = (_Float16)acc[mi][ni][r];
            }
}

// ---------------------------------------------------------------------------
// GEMM2: 256x256 tile, BK=64, 8 waves, 8-phase schedule with counted vmcnt
// (T3+T4) + setprio (T5), swizzled conflict-free LDS (T2). (R1 kernel,
// unchanged: 128.4 us, MfmaUtil 44, 1073 TF.)
__global__ __launch_bounds__(512, 2) void gemm2_kernel(const _Float16* __restrict__ Vt,
                                                       const _Float16* __restrict__ att0,
                                                       const _Float16* __restrict__ att1,
                                                       _Float16* __restrict__ OTh) {
    __shared__ __align__(16) _Float16 As[2][2][8192];   // [buf][kh][256*32]
    __shared__ __align__(16) _Float16 Bs[2][2][8192];
    const int z = blockIdx.z;
    const _Float16* A = Vt + (size_t)z * 8388608;
    const _Float16* Bt = z ? att1 : att0;
    _Float16* C = OTh + (size_t)z * 8388608;
    const int tid = threadIdx.x;
    const int lane = tid & 63;
    const int wave = tid >> 6;
    const int quad = lane >> 4;
    const int l16 = lane & 15;
    const int wm = wave >> 2;   // 0..1 -> 128-row half of M-tile
    const int wn = wave & 3;    // 0..3 -> 64-col slice of N-tile
    const int bm = blockIdx.y * 256;
    const int bn = blockIdx.x * 256;

    f32x4 acc[8][4] = {};
    f16x8 afr[4], bfr[4];

    const int s0 = tid, s1 = 512 + tid;
    const int sr0 = s0 >> 2, sr1 = s1 >> 2;
    const int r0 = sr0 ^ ((sr0 >> 2) & 1);
    const int r1 = sr1 ^ ((sr1 >> 2) & 1);
    const int q0 = (s0 & 3) ^ (r0 & 3);
    const int q1 = (s1 & 3) ^ (r1 & 3);
    const int offA0 = (bm + r0) * 4096 + q0 * 8;
    const int offA1 = (bm + r1) * 4096 + q1 * 8;
    const int offB0 = (bn + r0) * 4096 + q0 * 8;
    const int offB1 = (bn + r1) * 4096 + q1 * 8;

#define STAGE_A(buf, kt, kh) do {                                          \
        gload16(A + offA0 + (kt) * 64 + (kh) * 32, &As[buf][kh][tid * 8]); \
        gload16(A + offA1 + (kt) * 64 + (kh) * 32, &As[buf][kh][4096 + tid * 8]); \
    } while (0)
#define STAGE_B(buf, kt, kh) do {                                          \
        gload16(Bt + offB0 + (kt) * 64 + (kh) * 32, &Bs[buf][kh][tid * 8]); \
        gload16(Bt + offB1 + (kt) * 64 + (kh) * 32, &Bs[buf][kh][4096 + tid * 8]); \
    } while (0)

    const int c2 = (l16 >> 2) & 1;
    const int rdoff = ((l16 ^ c2) * 32) + ((quad ^ (l16 & 3)) * 8);  // halfs

    auto LDA = [&](int buf, int kh, int mh) {
        #pragma unroll
        for (int mi = 0; mi < 4; ++mi)
            afr[mi] = *(const f16x8*)&As[buf][kh][(wm * 128 + (mh * 4 + mi) * 16) * 32 + rdoff];
    };
    auto LDB = [&](int buf, int kh) {
        #pragma unroll
        for (int ni = 0; ni < 4; ++ni)
            bfr[ni] = *(const f16x8*)&Bs[buf][kh][(wn * 64 + ni * 16) * 32 + rdoff];
    };
    auto MM = [&](int mh) {
        __builtin_amdgcn_s_setprio(1);
        #pragma unroll
        for (int mi = 0; mi < 4; ++mi)
            #pragma unroll
            for (int ni = 0; ni < 4; ++ni)
                acc[mh * 4 + mi][ni] = __builtin_amdgcn_mfma_f32_16x16x32_f16(
                    afr[mi], bfr[ni], acc[mh * 4 + mi][ni], 0, 0, 0);
        __builtin_amdgcn_s_setprio(0);
    };

    STAGE_A(0, 0, 0); STAGE_B(0, 0, 0);
    STAGE_A(0, 0, 1); STAGE_B(0, 0, 1);
    STAGE_A(1, 1, 0); STAGE_B(1, 1, 0);
    WAITV(4);
    bar();

    #pragma unroll 1
    for (int i = 0; i < 31; ++i) {
        const int t0 = 2 * i;
        LDA(0, 0, 0); LDB(0, 0); STAGE_A(1, t0 + 1, 1);
        bar(); MM(0); bar();
        LDA(0, 0, 1); STAGE_B(1, t0 + 1, 1);
        bar(); MM(1); bar();
        LDA(0, 1, 0); LDB(0, 1); STAGE_A(0, t0 + 2, 0);
        bar(); MM(0); bar();
        LDA(0, 1, 1); STAGE_B(0, t0 + 2, 0);
        bar(); MM(1); WAITV(4); bar();
        LDA(1, 0, 0); LDB(1, 0); STAGE_A(0, t0 + 2, 1);
        bar(); MM(0); bar();
        LDA(1, 0, 1); STAGE_B(0, t0 + 2, 1);
        bar(); MM(1); bar();
        LDA(1, 1, 0); LDB(1, 1); STAGE_A(1, t0 + 3, 0);
        bar(); MM(0); bar();
        LDA(1, 1, 1); STAGE_B(1, t0 + 3, 0);
        bar(); MM(1); WAITV(4); bar();
    }

    // epilogue: tiles 62 (buf0), 63 (buf1); only buf1.Kh1 still to stage
    LDA(0, 0, 0); LDB(0, 0); STAGE_A(1, 63, 1);
    bar(); MM(0); bar();
    LDA(0, 0, 1); STAGE_B(1, 63, 1);
    bar(); MM(1); bar();
    LDA(0, 1, 0); LDB(0, 1);
    bar(); MM(0); bar();
    LDA(0, 1, 1);
    bar(); MM(1); WAITV(0); bar();
    LDA(1, 0, 0); LDB(1, 0); bar(); MM(0); bar();
    LDA(1, 0, 1);            bar(); MM(1); bar();
    LDA(1, 1, 0); LDB(1, 1); bar(); MM(0); bar();
    LDA(1, 1, 1);            bar(); MM(1); bar();

#undef STAGE_A
#undef STAGE_B

    #pragma unroll
    for (int mi = 0; mi < 8; ++mi)
        #pragma unroll
        for (int ni = 0; ni < 4; ++ni)
            #pragma unroll
            for (int r = 0; r < 4; ++r) {
                int row = bm + wm * 128 + mi * 16 + quad * 4 + r;
                int col = bn + wn * 64 + ni * 16 + l16;
                C[(size_t)row * 4096 + col] = (_Float16)acc[mi][ni][r];
            }
}

// ---------------------------------------------------------------------------
// Fused double 3-tap "fuse" + mask + softmax (R8 body, XCD swizzle, both
// batches in one dispatch).
__global__ __launch_bounds__(256) void fuse_softmax_kernel(const _Float16* __restrict__ S0,
                                                           const float* __restrict__ mm,
                                                           _Float16* __restrict__ att0,
                                                           _Float16* __restrict__ att1) {
    __shared__ float red[4];
    const int tid = threadIdx.x;
    const int lane = tid & 63;
    const int wave = tid >> 6;
    int g = blockIdx.x;
    int p_global = ((g & 7) << 10) | (g >> 3);
    const int bb = p_global >> 12;
    const int p = p_global & 4095;
    const _Float16* S = S0 + (size_t)bb * 16777216;
    _Float16* att = bb ? att1 : att0;
    const int pbase = ((p & 63) << 6) | (p >> 6);  // T(p)

    float acc[16];
    #pragma unroll
    for (int k = 0; k < 16; ++k) acc[k] = 0.f;

    #pragma unroll
    for (int t2 = -1; t2 <= 1; ++t2) {
        int b2 = pbase + t2;
        if ((unsigned)b2 >= 4096u) continue;
        int pp = ((b2 & 63) << 6) | (b2 >> 6);
        #pragma unroll
        for (int t1 = -1; t1 <= 1; ++t1) {
            int rr = pp + t1;
            if ((unsigned)rr >= 4096u) continue;
            const _Float16* row = S + (size_t)rr * 4096;
            #pragma unroll
            for (int k = 0; k < 16; ++k) {
                int l = k * 256 + tid;
                int i = (k * 256 + wave * 64) >> 6;
                int it2 = i + t2;
                if (it2 >= 0 && it2 < 64) {
                    int c = l + t2 * 64 + t1;
                    if ((unsigned)c < 4096u)
                        acc[k] += (float)row[c];
                } else if (it2 == 64) {
                    if (lane <= 62) {
                        int c = lane + 1 + t1;
                        if ((unsigned)c < 4096u) acc[k] += (float)row[c];
                    }
                } else {
                    if (lane >= 1) {
                        int c = 4031 + lane + t1;
                        if ((unsigned)c < 4096u) acc[k] += (float)row[c];
                    }
                }
            }
        }
    }

    float mv[16];
    float lmax = -1e30f;
    #pragma unroll
    for (int k = 0; k < 16; ++k) {
        int l = k * 256 + tid;
        mv[k] = mm[l];
        float lg = acc[k] * mv[k] * 10.0f;
        acc[k] = lg;
        lmax = fmaxf(lmax, lg);
    }
    #pragma unroll
    for (int off = 32; off > 0; off >>= 1) lmax = fmaxf(lmax, __shfl_xor(lmax, off));
    if (lane == 0) red[wave] = lmax;
    __syncthreads();
    lmax = fmaxf(fmaxf(red[0], red[1]), fmaxf(red[2], red[3]));
    __syncthreads();

    float lsum = 0.f;
    #pragma unroll
    for (int k = 0; k < 16; ++k) {
        float e = __expf(acc[k] - lmax);
        acc[k] = e;
        lsum += e;
    }
    #pragma unroll
    for (int off = 32; off > 0; off >>= 1) lsum += __shfl_xor(lsum, off);
    if (lane == 0) red[wave] = lsum;
    __syncthreads();
    float inv = 1.0f / (red[0] + red[1] + red[2] + red[3]);
    #pragma unroll
    for (int k = 0; k < 16; ++k) {
        int l = k * 256 + tid;
        att[(size_t)p * 4096 + l] = (_Float16)(acc[k] * inv * mv[k]);
    }
}

// ---------------------------------------------------------------------------
__global__ __launch_bounds__(256) void assemble_kernel(const _Float16* __restrict__ OTh,
                                                       float* __restrict__ out) {
    int idx = blockIdx.x * 256 + threadIdx.x;
    int bb = idx >> 21;
    int w = idx & 2097151;
    const _Float16* OTb = OTh + (size_t)bb * 8388608;
    int x = w & 127, y = (w >> 7) & 127, c = w >> 14;
    int r0 = (y + 1) & 1, s0 = (x + 1) & 1;
    float acc = 0.f;
    #pragma unroll
    for (int a = 0; a < 2; ++a) {
        int rh = r0 + 2 * a;
        int ph = (y + 1 - rh) >> 1;
        if ((unsigned)ph < 64u) {
            #pragma unroll
            for (int bq = 0; bq < 2; ++bq) {
                int rw = s0 + 2 * bq;
                int pw = (x + 1 - rw) >> 1;
                if ((unsigned)pw < 64u)
                    acc += (float)OTb[(size_t)(c * 16 + rh * 4 + rw) * 4096 + ph * 64 + pw];
            }
        }
    }
    out[idx] = 0.25f * acc;
}

// ---------------------------------------------------------------------------
extern "C" void kernel_launch(void* const* d_in, const int* in_sizes, int n_in,
                              void* d_out, int out_size, void* d_ws, size_t ws_size,
                              hipStream_t stream) {
    const float* f = (const float*)d_in[0];
    const float* b = (const float*)d_in[1];
    const float* mask = (const float*)d_in[2];
    float* out = (float*)d_out;
    char* ws = (char*)d_ws;

    // workspace — total 138,428,416 bytes (proven size)
    //   mm   : ws + 0              (16 KB)
    //   A    : ws + 16384          (37,748,736)  Fp+Wn  -> att0 (33.55M) after gemm1
    //   B    : ws + 37,765,120     (67,108,864)  S0(2x) -> Vt + OTh after fuse
    //   C    : ws + 104,873,984    (33,554,432)  fds/bds (8MB) -> att1
    float* mm = (float*)ws;
    _Float16* Fp = (_Float16*)(ws + 16384);
    _Float16* Wn = (_Float16*)(ws + 16384 + 18874368);
    _Float16* att0 = (_Float16*)(ws + 16384);                 // overlays Fp/Wn (dead)
    _Float16* S0 = (_Float16*)(ws + 37765120);
    _Float16* Vt = (_Float16*)(ws + 37765120);                // overlays S0 b0 (dead)
    _Float16* OTh = (_Float16*)(ws + 37765120 + 33554432);    // overlays S0 b1 (dead)
    float* fds = (float*)(ws + 104873984);
    float* bds = (float*)(ws + 104873984 + 4194304);
    _Float16* att1 = (_Float16*)(ws + 104873984);             // overlays fds/bds (dead)

    downsample_kernel<<<dim3(4096, 2), 256, 0, stream>>>(f, b, fds, bds);
    build_mm_kernel<<<16, 256, 0, stream>>>(mask, mm);
    build_fpatch_kernel<<<8192, 256, 0, stream>>>(fds, Fp);
    build_wn_kernel<<<8192, 256, 0, stream>>>(bds, Wn);

    gemm1_kernel<<<dim3(16, 16, 2), 512, 0, stream>>>(Fp, Wn, S0);
    fuse_softmax_kernel<<<8192, 256, 0, stream>>>(S0, mm, att0, att1);

    build_vt_kernel<<<4096, 256, 0, stream>>>(b, Vt);
    gemm2_kernel<<<dim3(16, 8, 2), 512, 0, stream>>>(Vt, att0, att1, OTh);
    assemble_kernel<<<16384, 256, 0, stream>>>(OTh, out);
}

// Round 3
// 431.088 us; speedup vs baseline: 1.0785x; 1.0071x over previous
//
#include <hip/hip_runtime.h>
#include <cstdint>

typedef _Float16 f16x8 __attribute__((ext_vector_type(8)));
typedef float f32x4 __attribute__((ext_vector_type(4)));

typedef __attribute__((address_space(1))) void gvoid;
typedef __attribute__((address_space(3))) void lvoid;

__device__ __forceinline__ void gload16(const void* g, void* l) {
    __builtin_amdgcn_global_load_lds((gvoid*)g, (lvoid*)l, 16, 0, 0);
}

__device__ __forceinline__ void bar() {
    asm volatile("" ::: "memory");
    __builtin_amdgcn_s_barrier();
    asm volatile("" ::: "memory");
}
#define WAITV(N) asm volatile("s_waitcnt vmcnt(" #N ")" ::: "memory")

// ---------------------------------------------------------------------------
__global__ __launch_bounds__(256) void downsample_kernel(const float* __restrict__ f,
                                                         const float* __restrict__ b,
                                                         float* __restrict__ fds,
                                                         float* __restrict__ bds) {
    int idx = blockIdx.x * 256 + threadIdx.x;
    const float* src = blockIdx.y ? b : f;
    float* dst = blockIdx.y ? bds : fds;
    int bb = idx >> 19;
    int r = idx & 524287;
    int c = r >> 12, a = (r >> 6) & 63, v = r & 63;
    dst[idx] = src[(size_t)bb * 2097152 + (size_t)c * 16384 + (2 * a) * 128 + 2 * v];
}

// ---------------------------------------------------------------------------
__global__ __launch_bounds__(256) void build_mm_kernel(const float* __restrict__ mask,
                                                       float* __restrict__ mm) {
    int l = blockIdx.x * 256 + threadIdx.x;
    if (l >= 4096) return;
    int i = l >> 6, j = l & 63;
    float s = 0.f;
    #pragma unroll
    for (int dy = 0; dy < 3; ++dy)
        #pragma unroll
        for (int dx = 0; dx < 3; ++dx) {
            int a = i + dy - 1, b = j + dx - 1;
            if ((unsigned)a < 64u && (unsigned)b < 64u)
                s += mask[(2 * a) * 128 + 2 * b];
        }
    mm[l] = (s == 0.0f) ? 1.0f : 0.0f;
}

// ---------------------------------------------------------------------------
__global__ __launch_bounds__(256) void build_fpatch_kernel(const float* __restrict__ fds,
                                                           _Float16* __restrict__ Fp) {
    int bb = blockIdx.x >> 12;
    int p = blockIdx.x & 4095;
    const float* fb = fds + (size_t)bb * 524288;
    _Float16* Fpb = Fp + (size_t)bb * 4718592;
    int u = p >> 6, v = p & 63;
    for (int k = threadIdx.x; k < 1152; k += 256) {
        int c = k / 9;
        int s = k - 9 * c;
        int dy = s / 3, dx = s - 3 * dy;
        int a = u + dy - 1, bcol = v + dx - 1;
        float val = 0.f;
        if ((unsigned)a < 64u && (unsigned)bcol < 64u)
            val = fb[c * 4096 + a * 64 + bcol];
        Fpb[(size_t)p * 1152 + k] = (_Float16)val;
    }
}

// ---------------------------------------------------------------------------
__global__ __launch_bounds__(256) void build_wn_kernel(const float* __restrict__ bds,
                                                       _Float16* __restrict__ Wn) {
    __shared__ float wsh[1152];
    __shared__ float red[4];
    int bb = blockIdx.x >> 12;
    int l = blockIdx.x & 4095;
    const float* bp = bds + (size_t)bb * 524288;
    _Float16* Wnb = Wn + (size_t)bb * 4718592;
    int i = l >> 6, j = l & 63;
    float sq = 0.f;
    for (int k = threadIdx.x; k < 1152; k += 256) {
        int c = k / 9;
        int s = k - 9 * c;
        int dy = s / 3, dx = s - 3 * dy;
        int a = i + dy - 1, bcol = j + dx - 1;
        float val = 0.f;
        if ((unsigned)a < 64u && (unsigned)bcol < 64u)
            val = bp[c * 4096 + a * 64 + bcol];
        wsh[k] = val;
        sq += val * val;
    }
    #pragma unroll
    for (int off = 32; off > 0; off >>= 1) sq += __shfl_xor(sq, off);
    if ((threadIdx.x & 63) == 0) red[threadIdx.x >> 6] = sq;
    __syncthreads();
    float total = red[0] + red[1] + red[2] + red[3] + 0.1152f;
    float rinv = 1.0f / sqrtf(total);
    for (int k = threadIdx.x; k < 1152; k += 256)
        Wnb[(size_t)l * 1152 + k] = (_Float16)(wsh[k] * rinv);
}

// ---------------------------------------------------------------------------
__global__ __launch_bounds__(256) void build_vt_kernel(const float* __restrict__ b,
                                                       _Float16* __restrict__ Vt) {
    int bb = blockIdx.x >> 11;
    int n = blockIdx.x & 2047;
    const float* bp = b + (size_t)bb * 2097152;
    _Float16* Vtb = Vt + (size_t)bb * 8388608;
    int c = n >> 4, r = n & 15, rh = r >> 2, rw = r & 3;
    const float* bc = bp + (size_t)c * 16384;
    for (int l = threadIdx.x; l < 4096; l += 256) {
        int lh = l >> 6, lw = l & 63;
        int row = 2 * lh + rh - 1, col = 2 * lw + rw - 1;
        float val = 0.f;
        if ((unsigned)row < 128u && (unsigned)col < 128u)
            val = bc[row * 128 + col];
        Vtb[(size_t)n * 4096 + l] = (_Float16)val;
    }
}

// ---------------------------------------------------------------------------
// Shared 256x256/BK=64 8-phase GEMM core with one-phase register prefetch:
// phase p = { STAGE; [vmcnt(4) @ p4,p8]; bar; LD(frags p+1); MM(p); bar }.
// ds_reads for p+1 execute on the LDS pipe WHILE the matrix pipe runs MM(p)
// (R2 counters showed read-burst and MFMA-burst serialized: 512+621 cyc).
// Ping-pong frags: afr parity flips every phase, bfr every 2 phases.
// vmcnt(4) depth re-derived for one-phase-early region completeness:
//   p4 wait leaves {U3,U4}: guarantees U1/U2 (needed by p6's LD) and
//   prev U7/U8 (needed by p4's LD). p8 wait leaves {U7,U8}: guarantees
//   U3/U4 (p8's LD) and U5/U6 (next p2's LD). Reads issue only after a
//   barrier following all waves' waits (collective guarantee).
// Accumulation order per element unchanged -> numerics identical.
template <int KSTR, int NTILES>
__device__ __forceinline__ void gemm_core(const _Float16* __restrict__ A,
                                          const _Float16* __restrict__ Bt,
                                          _Float16* __restrict__ C,
                                          _Float16* __restrict__ AsB,
                                          _Float16* __restrict__ BsB) {
    const int tid = threadIdx.x;
    const int lane = tid & 63;
    const int wave = tid >> 6;
    const int quad = lane >> 4;
    const int l16 = lane & 15;
    const int wm = wave >> 2;
    const int wn = wave & 3;
    const int bm = blockIdx.y * 256;
    const int bn = blockIdx.x * 256;

    f32x4 acc[8][4] = {};
    f16x8 afr[2][4], bfr[2][4];

    const int s0 = tid, s1 = 512 + tid;
    const int sr0 = s0 >> 2, sr1 = s1 >> 2;
    const int r0 = sr0 ^ ((sr0 >> 2) & 1);
    const int r1 = sr1 ^ ((sr1 >> 2) & 1);
    const int q0 = (s0 & 3) ^ (r0 & 3);
    const int q1 = (s1 & 3) ^ (r1 & 3);
    const int offA0 = (bm + r0) * KSTR + q0 * 8;
    const int offA1 = (bm + r1) * KSTR + q1 * 8;
    const int offB0 = (bn + r0) * KSTR + q0 * 8;
    const int offB1 = (bn + r1) * KSTR + q1 * 8;

#define STAGE_A(buf, kt, kh) do {                                                          \
        gload16(A + offA0 + (kt) * 64 + (kh) * 32, AsB + ((buf) * 2 + (kh)) * 8192 + tid * 8); \
        gload16(A + offA1 + (kt) * 64 + (kh) * 32, AsB + ((buf) * 2 + (kh)) * 8192 + 4096 + tid * 8); \
    } while (0)
#define STAGE_B(buf, kt, kh) do {                                                          \
        gload16(Bt + offB0 + (kt) * 64 + (kh) * 32, BsB + ((buf) * 2 + (kh)) * 8192 + tid * 8); \
        gload16(Bt + offB1 + (kt) * 64 + (kh) * 32, BsB + ((buf) * 2 + (kh)) * 8192 + 4096 + tid * 8); \
    } while (0)

    const int c2 = (l16 >> 2) & 1;
    const int rdoff = ((l16 ^ c2) * 32) + ((quad ^ (l16 & 3)) * 8);

#define LDA(par, buf, kh, mh) do {                                                         \
        _Pragma("unroll")                                                                  \
        for (int mi = 0; mi < 4; ++mi)                                                     \
            afr[par][mi] = *(const f16x8*)&AsB[((buf) * 2 + (kh)) * 8192 +                 \
                (wm * 128 + ((mh) * 4 + mi) * 16) * 32 + rdoff];                           \
    } while (0)
#define LDB(par, buf, kh) do {                                                             \
        _Pragma("unroll")                                                                  \
        for (int ni = 0; ni < 4; ++ni)                                                     \
            bfr[par][ni] = *(const f16x8*)&BsB[((buf) * 2 + (kh)) * 8192 +                 \
                (wn * 64 + ni * 16) * 32 + rdoff];                                         \
    } while (0)
#define MM(apar, bpar, mh) do {                                                            \
        __builtin_amdgcn_s_setprio(1);                                                     \
        _Pragma("unroll")                                                                  \
        for (int mi = 0; mi < 4; ++mi)                                                     \
            _Pragma("unroll")                                                              \
            for (int ni = 0; ni < 4; ++ni)                                                 \
                acc[(mh) * 4 + mi][ni] = __builtin_amdgcn_mfma_f32_16x16x32_f16(           \
                    afr[apar][mi], bfr[bpar][ni], acc[(mh) * 4 + mi][ni], 0, 0, 0);        \
        __builtin_amdgcn_s_setprio(0);                                                     \
    } while (0)

    // prologue: stage buf0 (tile0) + buf1.kh0 (tile1); preload p1's frags
    STAGE_A(0, 0, 0); STAGE_B(0, 0, 0);
    STAGE_A(0, 0, 1); STAGE_B(0, 0, 1);
    STAGE_A(1, 1, 0); STAGE_B(1, 1, 0);
    WAITV(4);
    bar();
    LDA(0, 0, 0, 0); LDB(0, 0, 0);

    #pragma unroll 1
    for (int i = 0; i < NTILES / 2 - 1; ++i) {
        const int t0 = 2 * i;
        // p1: compute buf0.kh0 quad0 | load p2 frags | stage buf1.kh1 <- t0+1
        STAGE_A(1, t0 + 1, 1); bar();
        LDA(1, 0, 0, 1); MM(0, 0, 0); bar();
        // p2
        STAGE_B(1, t0 + 1, 1); bar();
        LDA(0, 0, 1, 0); LDB(1, 0, 1); MM(1, 0, 1); bar();
        // p3: stage buf0.kh0 <- t0+2
        STAGE_A(0, t0 + 2, 0); bar();
        LDA(1, 0, 1, 1); MM(0, 1, 0); bar();
        // p4
        STAGE_B(0, t0 + 2, 0); WAITV(4); bar();
        LDA(0, 1, 0, 0); LDB(0, 1, 0); MM(1, 1, 1); bar();
        // p5: stage buf0.kh1 <- t0+2
        STAGE_A(0, t0 + 2, 1); bar();
        LDA(1, 1, 0, 1); MM(0, 0, 0); bar();
        // p6
        STAGE_B(0, t0 + 2, 1); bar();
        LDA(0, 1, 1, 0); LDB(1, 1, 1); MM(1, 0, 1); bar();
        // p7: stage buf1.kh0 <- t0+3
        STAGE_A(1, t0 + 3, 0); bar();
        LDA(1, 1, 1, 1); MM(0, 1, 0); bar();
        // p8
        STAGE_B(1, t0 + 3, 0); WAITV(4); bar();
        LDA(0, 0, 0, 0); LDB(0, 0, 0); MM(1, 1, 1); bar();
    }

    // epilogue: tiles NTILES-2 (buf0), NTILES-1 (buf1); stage buf1.kh1 only
    STAGE_A(1, NTILES - 1, 1); bar();
    LDA(1, 0, 0, 1); MM(0, 0, 0); bar();
    STAGE_B(1, NTILES - 1, 1); bar();
    LDA(0, 0, 1, 0); LDB(1, 0, 1); MM(1, 0, 1); bar();
    LDA(1, 0, 1, 1); MM(0, 1, 0); bar();
    WAITV(0); bar();
    LDA(0, 1, 0, 0); LDB(0, 1, 0); MM(1, 1, 1); bar();
    LDA(1, 1, 0, 1); MM(0, 0, 0); bar();
    LDA(0, 1, 1, 0); LDB(1, 1, 1); MM(1, 0, 1); bar();
    LDA(1, 1, 1, 1); MM(0, 1, 0); bar();
    MM(1, 1, 1);

#undef STAGE_A
#undef STAGE_B
#undef LDA
#undef LDB
#undef MM

    #pragma unroll
    for (int mi = 0; mi < 8; ++mi)
        #pragma unroll
        for (int ni = 0; ni < 4; ++ni)
            #pragma unroll
            for (int r = 0; r < 4; ++r) {
                int row = bm + wm * 128 + mi * 16 + quad * 4 + r;
                int col = bn + wn * 64 + ni * 16 + l16;
                C[(size_t)row * 4096 + col] = (_Float16)acc[mi][ni][r];
            }
}

// ---------------------------------------------------------------------------
__global__ __launch_bounds__(512, 2) void gemm1_kernel(const _Float16* __restrict__ Fp,
                                                       const _Float16* __restrict__ Wn,
                                                       _Float16* __restrict__ S0) {
    __shared__ __align__(16) _Float16 As[2][2][8192];
    __shared__ __align__(16) _Float16 Bs[2][2][8192];
    const int z = blockIdx.z;
    gemm_core<1152, 18>(Fp + (size_t)z * 4718592, Wn + (size_t)z * 4718592,
                        S0 + (size_t)z * 16777216, &As[0][0][0], &Bs[0][0][0]);
}

// ---------------------------------------------------------------------------
__global__ __launch_bounds__(512, 2) void gemm2_kernel(const _Float16* __restrict__ Vt,
                                                       const _Float16* __restrict__ att0,
                                                       const _Float16* __restrict__ att1,
                                                       _Float16* __restrict__ OTh) {
    __shared__ __align__(16) _Float16 As[2][2][8192];
    __shared__ __align__(16) _Float16 Bs[2][2][8192];
    const int z = blockIdx.z;
    gemm_core<4096, 64>(Vt + (size_t)z * 8388608, z ? att1 : att0,
                        OTh + (size_t)z * 8388608, &As[0][0][0], &Bs[0][0][0]);
}

// ---------------------------------------------------------------------------
// Fused double 3-tap "fuse" + mask + softmax (R8 body, XCD swizzle, both
// batches in one dispatch).
__global__ __launch_bounds__(256) void fuse_softmax_kernel(const _Float16* __restrict__ S0,
                                                           const float* __restrict__ mm,
                                                           _Float16* __restrict__ att0,
                                                           _Float16* __restrict__ att1) {
    __shared__ float red[4];
    const int tid = threadIdx.x;
    const int lane = tid & 63;
    const int wave = tid >> 6;
    int g = blockIdx.x;
    int p_global = ((g & 7) << 10) | (g >> 3);
    const int bb = p_global >> 12;
    const int p = p_global & 4095;
    const _Float16* S = S0 + (size_t)bb * 16777216;
    _Float16* att = bb ? att1 : att0;
    const int pbase = ((p & 63) << 6) | (p >> 6);  // T(p)

    float acc[16];
    #pragma unroll
    for (int k = 0; k < 16; ++k) acc[k] = 0.f;

    #pragma unroll
    for (int t2 = -1; t2 <= 1; ++t2) {
        int b2 = pbase + t2;
        if ((unsigned)b2 >= 4096u) continue;
        int pp = ((b2 & 63) << 6) | (b2 >> 6);
        #pragma unroll
        for (int t1 = -1; t1 <= 1; ++t1) {
            int rr = pp + t1;
            if ((unsigned)rr >= 4096u) continue;
            const _Float16* row = S + (size_t)rr * 4096;
            #pragma unroll
            for (int k = 0; k < 16; ++k) {
                int l = k * 256 + tid;
                int i = (k * 256 + wave * 64) >> 6;
                int it2 = i + t2;
                if (it2 >= 0 && it2 < 64) {
                    int c = l + t2 * 64 + t1;
                    if ((unsigned)c < 4096u)
                        acc[k] += (float)row[c];
                } else if (it2 == 64) {
                    if (lane <= 62) {
                        int c = lane + 1 + t1;
                        if ((unsigned)c < 4096u) acc[k] += (float)row[c];
                    }
                } else {
                    if (lane >= 1) {
                        int c = 4031 + lane + t1;
                        if ((unsigned)c < 4096u) acc[k] += (float)row[c];
                    }
                }
            }
        }
    }

    float mv[16];
    float lmax = -1e30f;
    #pragma unroll
    for (int k = 0; k < 16; ++k) {
        int l = k * 256 + tid;
        mv[k] = mm[l];
        float lg = acc[k] * mv[k] * 10.0f;
        acc[k] = lg;
        lmax = fmaxf(lmax, lg);
    }
    #pragma unroll
    for (int off = 32; off > 0; off >>= 1) lmax = fmaxf(lmax, __shfl_xor(lmax, off));
    if (lane == 0) red[wave] = lmax;
    __syncthreads();
    lmax = fmaxf(fmaxf(red[0], red[1]), fmaxf(red[2], red[3]));
    __syncthreads();

    float lsum = 0.f;
    #pragma unroll
    for (int k = 0; k < 16; ++k) {
        float e = __expf(acc[k] - lmax);
        acc[k] = e;
        lsum += e;
    }
    #pragma unroll
    for (int off = 32; off > 0; off >>= 1) lsum += __shfl_xor(lsum, off);
    if (lane == 0) red[wave] = lsum;
    __syncthreads();
    float inv = 1.0f / (red[0] + red[1] + red[2] + red[3]);
    #pragma unroll
    for (int k = 0; k < 16; ++k) {
        int l = k * 256 + tid;
        att[(size_t)p * 4096 + l] = (_Float16)(acc[k] * inv * mv[k]);
    }
}

// ---------------------------------------------------------------------------
__global__ __launch_bounds__(256) void assemble_kernel(const _Float16* __restrict__ OTh,
                                                       float* __restrict__ out) {
    int idx = blockIdx.x * 256 + threadIdx.x;
    int bb = idx >> 21;
    int w = idx & 2097151;
    const _Float16* OTb = OTh + (size_t)bb * 8388608;
    int x = w & 127, y = (w >> 7) & 127, c = w >> 14;
    int r0 = (y + 1) & 1, s0 = (x + 1) & 1;
    float acc = 0.f;
    #pragma unroll
    for (int a = 0; a < 2; ++a) {
        int rh = r0 + 2 * a;
        int ph = (y + 1 - rh) >> 1;
        if ((unsigned)ph < 64u) {
            #pragma unroll
            for (int bq = 0; bq < 2; ++bq) {
                int rw = s0 + 2 * bq;
                int pw = (x + 1 - rw) >> 1;
                if ((unsigned)pw < 64u)
                    acc += (float)OTb[(size_t)(c * 16 + rh * 4 + rw) * 4096 + ph * 64 + pw];
            }
        }
    }
    out[idx] = 0.25f * acc;
}

// ---------------------------------------------------------------------------
extern "C" void kernel_launch(void* const* d_in, const int* in_sizes, int n_in,
                              void* d_out, int out_size, void* d_ws, size_t ws_size,
                              hipStream_t stream) {
    const float* f = (const float*)d_in[0];
    const float* b = (const float*)d_in[1];
    const float* mask = (const float*)d_in[2];
    float* out = (float*)d_out;
    char* ws = (char*)d_ws;

    // workspace — total 138,428,416 bytes (proven size)
    float* mm = (float*)ws;
    _Float16* Fp = (_Float16*)(ws + 16384);
    _Float16* Wn = (_Float16*)(ws + 16384 + 18874368);
    _Float16* att0 = (_Float16*)(ws + 16384);                 // overlays Fp/Wn (dead)
    _Float16* S0 = (_Float16*)(ws + 37765120);
    _Float16* Vt = (_Float16*)(ws + 37765120);                // overlays S0 b0 (dead)
    _Float16* OTh = (_Float16*)(ws + 37765120 + 33554432);    // overlays S0 b1 (dead)
    float* fds = (float*)(ws + 104873984);
    float* bds = (float*)(ws + 104873984 + 4194304);
    _Float16* att1 = (_Float16*)(ws + 104873984);             // overlays fds/bds (dead)

    downsample_kernel<<<dim3(4096, 2), 256, 0, stream>>>(f, b, fds, bds);
    build_mm_kernel<<<16, 256, 0, stream>>>(mask, mm);
    build_fpatch_kernel<<<8192, 256, 0, stream>>>(fds, Fp);
    build_wn_kernel<<<8192, 256, 0, stream>>>(bds, Wn);

    gemm1_kernel<<<dim3(16, 16, 2), 512, 0, stream>>>(Fp, Wn, S0);
    fuse_softmax_kernel<<<8192, 256, 0, stream>>>(S0, mm, att0, att1);

    build_vt_kernel<<<4096, 256, 0, stream>>>(b, Vt);
    gemm2_kernel<<<dim3(16, 8, 2), 512, 0, stream>>>(Vt, att0, att1, OTh);
    assemble_kernel<<<16384, 256, 0, stream>>>(OTh, out);
}